// Round 4
// baseline (453.521 us; speedup 1.0000x reference)
//
#include <hip/hip_runtime.h>

// Problem constants
#define BB 64
#define CC 3
#define HH 512
#define WW 512
#define PP 16
#define IN_F 256
#define HD 512
#define PATCH_DIM 768   // 16*16*3
#define NB_M2 512       // 256 rows x 2 col-tiles of 128
#define NB_PATCH (BB * CC * 16)   // 3072
#define NB_FUSE BB                // 64

// native clang vector for nontemporal builtin (HIP float4 is a struct -> rejected)
typedef float floatx4 __attribute__((ext_vector_type(4)));

// ---------------------------------------------------------------------------
// Math collapse: softmax over a size-1 axis == 1, so attn is all-ones and
//   out[b,h,d] = sum_n feat_h[b,h,n,d]
// Linearity lets the patch-sum move to the front, and Wm@Wo pre-associates:
//   S[b,k]   = sum_{h,w} feature[b, c, 16h+p1, 16w+p2],  k=(p1*16+p2)*3+c
//   M2       = W @ W_out                          (256x256, weights-only)
//   t1       = S @ W_patch + 1024*b_patch         (768 -> 256)
//   z        = t1 @ M2                            (256 -> 256)
//   x        = 0.25*(z + b_out) + 0.75*token
//   out      = LayerNorm(x)*gamma + beta
//
// Single-launch producer/consumer: fuse block b needs only the 48 patch
// blocks of batch b (+ M2). Patch blocks release-add a per-batch counter;
// fuse blocks (last in grid) acquire-spin, so their ~6 us of GEMV work hides
// under the HBM-bound patch stream and one launch gap disappears.
// Deadlock-free: 64 spinning 256-thread blocks can't exhaust residency and
// producers never wait on consumers.
// ---------------------------------------------------------------------------

__global__ __launch_bounds__(256)
void mega_kernel(const float* __restrict__ feature,
                 const float* __restrict__ W,
                 const float* __restrict__ Wo,
                 const float* __restrict__ Wp,
                 const float* __restrict__ bp,
                 const float* __restrict__ bo,
                 const float* __restrict__ tok,
                 const float* __restrict__ gamma,
                 const float* __restrict__ beta,
                 float* __restrict__ S,
                 float* __restrict__ M2,
                 int* __restrict__ ctr,     // ctr[0..63] = per-batch, ctr[64] = M2
                 float* __restrict__ out)
{
    int bid = blockIdx.x;
    int t = threadIdx.x;

    if (bid < NB_M2) {
        // ---- M2 path: M2[i, ct*128 .. +128) = sum_k W[i,k] * Wo[k, ...] ----
        __shared__ float sW[HD];            // W row i (2 KB)
        __shared__ float partm[4][128];     // [kg][col] partials (2 KB)

        int i  = bid >> 1;
        int ct = bid & 1;

        sW[t]       = W[(size_t)i * HD + t];
        sW[t + 256] = W[(size_t)i * HD + t + 256];
        __syncthreads();

        int tc = t & 63;          // thread-col slot (owns 2 cols)
        int kg = t >> 6;          // 0..3, k-range [kg*128, +128)
        int j  = ct * 128 + tc * 2;

        float a0 = 0.f, a1 = 0.f;
        const float* wb = Wo + j;
#pragma unroll 8
        for (int k = kg * 128; k < kg * 128 + 128; ++k) {
            float2 w = *(const float2*)(wb + (size_t)k * IN_F);
            float s = sW[k];
            a0 += s * w.x;
            a1 += s * w.y;
        }
        partm[kg][tc * 2]     = a0;
        partm[kg][tc * 2 + 1] = a1;
        __syncthreads();

        if (t < 128) {
            float s = partm[0][t] + partm[1][t] + partm[2][t] + partm[3][t];
            M2[(size_t)i * IN_F + ct * 128 + t] = s;
        }
        __syncthreads();
        if (t == 0)
            __hip_atomic_fetch_add(&ctr[BB], 1, __ATOMIC_RELEASE,
                                   __HIP_MEMORY_SCOPE_AGENT);
        return;
    }

    if (bid < NB_M2 + NB_PATCH) {
        // ---- Patch-reduce path (proven):
        // S[b, (p1*16+p2)*3 + c] = sum_{h,w} feature[b, c, 16h+p1, 16w+p2]
        int pbid = bid - NB_M2;
        int p1 = pbid & 15;
        int tmp = pbid >> 4;
        int c = tmp % 3;
        int b = tmp / 3;

        const size_t base_bc = (size_t)(b * 3 + c) * (size_t)(HH * WW);

        float acc[4] = {0.f, 0.f, 0.f, 0.f};

#pragma unroll
        for (int i = 0; i < 16; ++i) {
            int idx = i * 256 + t;        // 0..4095
            int h = idx >> 7;             // 0..31
            int u = idx & 127;            // float4-chunk within row
            size_t off = base_bc + (size_t)(p1 + 16 * h) * WW + (size_t)u * 4;
            floatx4 v = __builtin_nontemporal_load((const floatx4*)(feature + off));
            acc[0] += v.x;
            acc[1] += v.y;
            acc[2] += v.z;
            acc[3] += v.w;
        }

        __shared__ float red[16 * 68];
        __shared__ float red2[16 * 8];
        int g = t >> 2;                  // 0..63
        int pb = (t & 3) * 4;
#pragma unroll
        for (int j = 0; j < 4; ++j)
            red[(pb + j) * 68 + g] = acc[j];
        __syncthreads();

        if (t < 128) {
            int bin = t >> 3;
            int l = t & 7;
            float s = 0.f;
#pragma unroll
            for (int q = 0; q < 8; ++q)
                s += red[bin * 68 + l + 8 * q];
            red2[bin * 8 + l] = s;
        }
        __syncthreads();

        if (t < 16) {
            float s = 0.f;
#pragma unroll
            for (int l = 0; l < 8; ++l)
                s += red2[t * 8 + l];
            S[(size_t)b * PATCH_DIM + (size_t)(p1 * 16 + t) * 3 + c] = s;
        }
        __syncthreads();
        if (t == 0)
            __hip_atomic_fetch_add(&ctr[b], 1, __ATOMIC_RELEASE,
                                   __HIP_MEMORY_SCOPE_AGENT);
        return;
    }

    // ---- Fuse path (256 threads): two-stage GEMV + LayerNorm for batch b ----
    {
        int b = bid - (NB_M2 + NB_PATCH);

        __shared__ float sS[PATCH_DIM];         // 768
        __shared__ float part1[4 * IN_F];       // stage-1 partials [kg][256]
        __shared__ float sT[IN_F];              // 256
        __shared__ float part2[4 * IN_F];       // stage-2 partials [kg][256]
        __shared__ float wred[8];
        __shared__ float stats[2];

        // Inputs independent of S: load while producers run.
        float bo_t    = bo[t];
        float tok_t   = tok[b * IN_F + t];
        float gamma_t = gamma[t];
        float beta_t  = beta[t];
        float bp_t    = bp[t];

        // Wait for this batch's 48 patch blocks and all 512 M2 blocks.
        if (t == 0) {
            while (__hip_atomic_load(&ctr[b], __ATOMIC_ACQUIRE,
                                     __HIP_MEMORY_SCOPE_AGENT) < 48 ||
                   __hip_atomic_load(&ctr[BB], __ATOMIC_ACQUIRE,
                                     __HIP_MEMORY_SCOPE_AGENT) < NB_M2) {
                __builtin_amdgcn_s_sleep(8);
            }
        }
        __syncthreads();

        for (int k = t; k < PATCH_DIM; k += 256)
            sS[k] = S[(size_t)b * PATCH_DIM + k];
        __syncthreads();

        // ---- Stage 1: t1 = S @ Wp + 1024*bp  (768 -> 256) ----
        {
            int j4 = (t & 63) * 4;
            int kg = t >> 6;              // 0..3, k in [kg*192, +192)
            float a0 = 0.f, a1 = 0.f, a2 = 0.f, a3 = 0.f;
            const float* wrow = Wp + (size_t)(kg * 192) * IN_F + j4;
#pragma unroll 8
            for (int i = 0; i < 192; ++i) {
                float s = sS[kg * 192 + i];
                float4 w = *(const float4*)(wrow + (size_t)i * IN_F);
                a0 += s * w.x; a1 += s * w.y; a2 += s * w.z; a3 += s * w.w;
            }
            part1[kg * IN_F + j4 + 0] = a0;
            part1[kg * IN_F + j4 + 1] = a1;
            part1[kg * IN_F + j4 + 2] = a2;
            part1[kg * IN_F + j4 + 3] = a3;
        }
        __syncthreads();
        sT[t] = part1[t] + part1[IN_F + t] + part1[2 * IN_F + t]
              + part1[3 * IN_F + t] + 1024.f * bp_t;
        __syncthreads();

        // ---- Stage 2: z = t1 @ M2  (256 -> 256) ----
        {
            int j4 = (t & 63) * 4;
            int kg = t >> 6;              // 0..3, k in [kg*64, +64)
            float a0 = 0.f, a1 = 0.f, a2 = 0.f, a3 = 0.f;
            const float* wrow = M2 + (size_t)(kg * 64) * IN_F + j4;
#pragma unroll 8
            for (int i = 0; i < 64; ++i) {
                float s = sT[kg * 64 + i];
                float4 w = *(const float4*)(wrow + (size_t)i * IN_F);
                a0 += s * w.x; a1 += s * w.y; a2 += s * w.z; a3 += s * w.w;
            }
            part2[kg * IN_F + j4 + 0] = a0;
            part2[kg * IN_F + j4 + 1] = a1;
            part2[kg * IN_F + j4 + 2] = a2;
            part2[kg * IN_F + j4 + 3] = a3;
        }
        __syncthreads();

        // ---- Epilogue: residual + LayerNorm (all 256 threads hold x) ----
        float z = part2[t] + part2[IN_F + t] + part2[2 * IN_F + t]
                + part2[3 * IN_F + t];
        float x = 0.25f * (z + bo_t) + 0.75f * tok_t;

        float s1 = x, s2 = x * x;
#pragma unroll
        for (int off = 32; off > 0; off >>= 1) {
            s1 += __shfl_down(s1, off);
            s2 += __shfl_down(s2, off);
        }
        int wave = t >> 6;               // 0..3
        if ((t & 63) == 0) {
            wred[wave * 2]     = s1;
            wred[wave * 2 + 1] = s2;
        }
        __syncthreads();
        if (t == 0) {
            float a1 = wred[0] + wred[2] + wred[4] + wred[6];
            float a2 = wred[1] + wred[3] + wred[5] + wred[7];
            float mu = a1 * (1.f / 256.f);
            float var = a2 * (1.f / 256.f) - mu * mu;
            stats[0] = mu;
            stats[1] = rsqrtf(var + 1e-5f);
        }
        __syncthreads();

        float y = (x - stats[0]) * stats[1] * gamma_t + beta_t;
        out[b * IN_F + t] = y;
    }
}

extern "C" void kernel_launch(void* const* d_in, const int* in_sizes, int n_in,
                              void* d_out, int out_size, void* d_ws, size_t ws_size,
                              hipStream_t stream)
{
    const float* token   = (const float*)d_in[0];
    const float* feature = (const float*)d_in[1];
    const float* W_patch = (const float*)d_in[2];
    const float* b_patch = (const float*)d_in[3];
    const float* W       = (const float*)d_in[4];
    // d_in[5] = a_self, d_in[6] = a_neigh : dead (softmax over size-1 axis == 1)
    const float* W_out   = (const float*)d_in[7];
    const float* b_out   = (const float*)d_in[8];
    const float* gamma   = (const float*)d_in[9];
    const float* beta    = (const float*)d_in[10];

    float* out = (float*)d_out;
    float* S   = (float*)d_ws;                 // 64*768 floats
    float* M2  = S + (size_t)BB * PATCH_DIM;   // 256*256 floats
    int*   ctr = (int*)(M2 + (size_t)IN_F * IN_F);  // 65 ints

    // Zero the sync counters (poisoned between iterations). Tiny, same stream.
    hipMemsetAsync(ctr, 0, (BB + 1) * sizeof(int), stream);

    // Single launch: M2 tiles (short) + patch stream (HBM-bound) + fuse
    // consumers (spin, then hide under the patch tail).
    dim3 grid(NB_M2 + NB_PATCH + NB_FUSE);
    mega_kernel<<<grid, 256, 0, stream>>>(feature, W, W_out, W_patch, b_patch,
                                          b_out, token, gamma, beta,
                                          S, M2, ctr, out);
}

// Round 5
// 285.447 us; speedup vs baseline: 1.5888x; 1.5888x over previous
//
#include <hip/hip_runtime.h>

// Problem constants
#define BB 64
#define CC 3
#define HH 512
#define WW 512
#define PP 16
#define IN_F 256
#define HD 512
#define PATCH_DIM 768   // 16*16*3
#define NB_M2 512       // 256 rows x 2 col-tiles of 128
#define NB_PATCH (BB * CC * 16)   // 3072
#define NQ 48           // partial-contribution blocks per batch (c,p1)

// native clang vector for nontemporal builtin (HIP float4 is a struct -> rejected)
typedef float floatx4 __attribute__((ext_vector_type(4)));

// ---------------------------------------------------------------------------
// Math collapse: softmax over a size-1 axis == 1, so attn is all-ones and
//   out[b,h,d] = sum_n feat_h[b,h,n,d]
// Linearity lets the patch-sum move to the front, and Wm@Wo pre-associates:
//   S[b,k]   = sum_{h,w} feature[b, c, 16h+p1, 16w+p2],  k=(p1*16+p2)*3+c
//   M2       = W @ W_out                          (256x256, weights-only)
//   t1       = S @ W_patch + 1024*b_patch         (768 -> 256)
//   z        = t1 @ M2                            (256 -> 256)
//   x        = 0.25*(z + b_out) + 0.75*token
//   out      = LayerNorm(x)*gamma + beta
//
// Stage-1 is DISTRIBUTED into the patch blocks: each patch block (b,c,p1)
// ends with a 16x256 GEMV of its 16 S-values against the matching 16 rows of
// W_patch (L3-hot, shared by all 64 batches) and writes a 256-float partial
// T1p[b][q][:]. No atomics, no sync — the launch boundary orders everything
// (round-4 lesson: acquire-spin + release atomics inside a BW-bound kernel
// invalidate L2 continuously and tank the stream to ~0.5 TB/s).
// Launch 2 shrinks to: sum 48 partials + 256x256 GEMV (M2) + LayerNorm.
// ---------------------------------------------------------------------------

// Kernel 1 (merged):
//   blocks [0, 512)     : M2 tile (row i = bid>>1, col-tile ct = bid&1)
//   blocks [512, 3584)  : patch reduce + distributed stage-1
__global__ __launch_bounds__(256)
void prep_kernel(const float* __restrict__ feature,
                 const float* __restrict__ W,
                 const float* __restrict__ Wo,
                 const float* __restrict__ Wp,
                 float* __restrict__ T1p,
                 float* __restrict__ M2)
{
    int bid = blockIdx.x;
    int t = threadIdx.x;

    if (bid < NB_M2) {
        // ---- M2 path: M2[i, ct*128 .. +128) = sum_k W[i,k] * Wo[k, ...] ----
        __shared__ float sW[HD];            // W row i (2 KB)
        __shared__ float partm[4][128];     // [kg][col] partials (2 KB)

        int i  = bid >> 1;
        int ct = bid & 1;

        sW[t]       = W[(size_t)i * HD + t];
        sW[t + 256] = W[(size_t)i * HD + t + 256];
        __syncthreads();

        int tc = t & 63;          // thread-col slot (owns 2 cols)
        int kg = t >> 6;          // 0..3, k-range [kg*128, +128)
        int j  = ct * 128 + tc * 2;

        float a0 = 0.f, a1 = 0.f;
        const float* wb = Wo + j;
#pragma unroll 8
        for (int k = kg * 128; k < kg * 128 + 128; ++k) {
            float2 w = *(const float2*)(wb + (size_t)k * IN_F);
            float s = sW[k];
            a0 += s * w.x;
            a1 += s * w.y;
        }
        partm[kg][tc * 2]     = a0;
        partm[kg][tc * 2 + 1] = a1;
        __syncthreads();

        if (t < 128) {
            float s = partm[0][t] + partm[1][t] + partm[2][t] + partm[3][t];
            M2[(size_t)i * IN_F + ct * 128 + t] = s;
        }
        return;
    }

    // ---- Patch-reduce path + distributed stage-1 ----
    // S_vals[p2] = sum_{h,w} feature[b, c, 16h+p1, 16w+p2], then
    // T1p[b][c*16+p1][j] = sum_{p2} S_vals[p2] * Wp[(p1*16+p2)*3+c, j]
    {
        int pbid = bid - NB_M2;
        int p1 = pbid & 15;
        int tmp = pbid >> 4;
        int c = tmp % 3;
        int b = tmp / 3;

        const size_t base_bc = (size_t)(b * 3 + c) * (size_t)(HH * WW);

        float acc[4] = {0.f, 0.f, 0.f, 0.f};

#pragma unroll
        for (int i = 0; i < 16; ++i) {
            int idx = i * 256 + t;        // 0..4095
            int h = idx >> 7;             // 0..31
            int u = idx & 127;            // float4-chunk within row
            size_t off = base_bc + (size_t)(p1 + 16 * h) * WW + (size_t)u * 4;
            floatx4 v = __builtin_nontemporal_load((const floatx4*)(feature + off));
            acc[0] += v.x;
            acc[1] += v.y;
            acc[2] += v.z;
            acc[3] += v.w;
        }

        __shared__ float red[16 * 68];
        __shared__ float red2[16 * 8];
        __shared__ float sS16[16];
        int g = t >> 2;                  // 0..63
        int pb = (t & 3) * 4;
#pragma unroll
        for (int j = 0; j < 4; ++j)
            red[(pb + j) * 68 + g] = acc[j];
        __syncthreads();

        if (t < 128) {
            int bin = t >> 3;
            int l = t & 7;
            float s = 0.f;
#pragma unroll
            for (int q = 0; q < 8; ++q)
                s += red[bin * 68 + l + 8 * q];
            red2[bin * 8 + l] = s;
        }
        __syncthreads();

        if (t < 16) {
            float s = 0.f;
#pragma unroll
            for (int l = 0; l < 8; ++l)
                s += red2[t * 8 + l];
            sS16[t] = s;
        }
        __syncthreads();

        // Distributed stage-1: 16x256 GEMV. Wp rows (p1*16+p2)*3+c are
        // L3-hot (only 768 KB unique, shared by all 64 batches).
        float a = 0.f;
        const float* wprow = Wp + (size_t)(p1 * 16 * 3 + c) * IN_F + t;
#pragma unroll 16
        for (int p2 = 0; p2 < 16; ++p2)
            a += sS16[p2] * wprow[(size_t)(p2 * 3) * IN_F];

        T1p[((size_t)b * NQ + (c * 16 + p1)) * IN_F + t] = a;
    }
}

// Kernel 2: per-batch partial-sum + stage-2 GEMV + LayerNorm.
// grid = 64 blocks, 256 threads.
__global__ __launch_bounds__(256)
void fuse_kernel(const float* __restrict__ T1p,
                 const float* __restrict__ bp,
                 const float* __restrict__ M2,
                 const float* __restrict__ bo,
                 const float* __restrict__ tok,
                 const float* __restrict__ gamma,
                 const float* __restrict__ beta,
                 float* __restrict__ out)
{
    int b = blockIdx.x;
    int t = threadIdx.x;

    __shared__ float sT[IN_F];              // t1 (256)
    __shared__ float part2[4 * IN_F];       // stage-2 partials [kg][256]
    __shared__ float wred[8];
    __shared__ float stats[2];

    float bo_t    = bo[t];
    float tok_t   = tok[b * IN_F + t];
    float gamma_t = gamma[t];
    float beta_t  = beta[t];
    float bp_t    = bp[t];

    // t1[t] = sum of 48 partials + 1024*bp
    {
        float s = 0.f;
        const float* p = T1p + (size_t)b * NQ * IN_F + t;
#pragma unroll 8
        for (int q = 0; q < NQ; ++q)
            s += p[(size_t)q * IN_F];
        sT[t] = s + 1024.f * bp_t;
    }
    __syncthreads();

    // ---- Stage 2: z = t1 @ M2  (256 -> 256) ----
    {
        int j4 = (t & 63) * 4;
        int kg = t >> 6;              // 0..3, k in [kg*64, +64)
        float a0 = 0.f, a1 = 0.f, a2 = 0.f, a3 = 0.f;
        const float* wrow = M2 + (size_t)(kg * 64) * IN_F + j4;
#pragma unroll 8
        for (int i = 0; i < 64; ++i) {
            float s = sT[kg * 64 + i];
            float4 w = *(const float4*)(wrow + (size_t)i * IN_F);
            a0 += s * w.x; a1 += s * w.y; a2 += s * w.z; a3 += s * w.w;
        }
        part2[kg * IN_F + j4 + 0] = a0;
        part2[kg * IN_F + j4 + 1] = a1;
        part2[kg * IN_F + j4 + 2] = a2;
        part2[kg * IN_F + j4 + 3] = a3;
    }
    __syncthreads();

    // ---- Epilogue: residual + LayerNorm (all 256 threads hold x) ----
    float z = part2[t] + part2[IN_F + t] + part2[2 * IN_F + t]
            + part2[3 * IN_F + t];
    float x = 0.25f * (z + bo_t) + 0.75f * tok_t;

    float s1 = x, s2 = x * x;
#pragma unroll
    for (int off = 32; off > 0; off >>= 1) {
        s1 += __shfl_down(s1, off);
        s2 += __shfl_down(s2, off);
    }
    int wave = t >> 6;               // 0..3
    if ((t & 63) == 0) {
        wred[wave * 2]     = s1;
        wred[wave * 2 + 1] = s2;
    }
    __syncthreads();
    if (t == 0) {
        float a1 = wred[0] + wred[2] + wred[4] + wred[6];
        float a2 = wred[1] + wred[3] + wred[5] + wred[7];
        float mu = a1 * (1.f / 256.f);
        float var = a2 * (1.f / 256.f) - mu * mu;
        stats[0] = mu;
        stats[1] = rsqrtf(var + 1e-5f);
    }
    __syncthreads();

    float y = (x - stats[0]) * stats[1] * gamma_t + beta_t;
    out[b * IN_F + t] = y;
}

extern "C" void kernel_launch(void* const* d_in, const int* in_sizes, int n_in,
                              void* d_out, int out_size, void* d_ws, size_t ws_size,
                              hipStream_t stream)
{
    const float* token   = (const float*)d_in[0];
    const float* feature = (const float*)d_in[1];
    const float* W_patch = (const float*)d_in[2];
    const float* b_patch = (const float*)d_in[3];
    const float* W       = (const float*)d_in[4];
    // d_in[5] = a_self, d_in[6] = a_neigh : dead (softmax over size-1 axis == 1)
    const float* W_out   = (const float*)d_in[7];
    const float* b_out   = (const float*)d_in[8];
    const float* gamma   = (const float*)d_in[9];
    const float* beta    = (const float*)d_in[10];

    float* out = (float*)d_out;
    float* T1p = (float*)d_ws;                       // 64*48*256 floats (3 MB)
    float* M2  = T1p + (size_t)BB * NQ * IN_F;       // 256*256 floats (256 KB)

    // Launch 1: fine-sharded M2 (short blocks) + patch reduce with
    // distributed stage-1 (HBM-bound, 201 MB compulsory).
    dim3 grid1(NB_M2 + NB_PATCH);
    prep_kernel<<<grid1, 256, 0, stream>>>(feature, W, W_out, W_patch,
                                           T1p, M2);

    // Launch 2: partial-sum + stage-2 GEMV + LayerNorm (tiny).
    fuse_kernel<<<BB, 256, 0, stream>>>(T1p, b_patch, M2, b_out,
                                        token, gamma, beta, out);
}